// Round 2
// baseline (399.388 us; speedup 1.0000x reference)
//
#include <hip/hip_runtime.h>
#include <math.h>

#define NFIELDS 10
#define VOCAB   100000
#define EDIM    8
#define BATCH   16384
#define NPAIR   45   // 10*9/2

// ---------------------------------------------------------------------------
// Phase A: one thread per (item, pair). blockIdx.y = pair (0..44),
// blockIdx.x = item chunk (256 items). Each thread issues 4 independent 16B
// gathers (both 32B V rows), dots them, and writes the partial coalesced to
// P[pair][item] in workspace. Consecutive blocks work on the same 6.4 MB
// (i,j)/(j,i) slice pair -> temporal L2/L3 locality.
// ---------------------------------------------------------------------------
__global__ __launch_bounds__(256) void ffm_pairs(
    const int*   __restrict__ x,   // (BATCH, NFIELDS)
    const float* __restrict__ V,   // (NFIELDS, NFIELDS, VOCAB, EDIM)
    float*       __restrict__ P)   // (NPAIR, BATCH) partial dots, in d_ws
{
    const int p = blockIdx.y;
    // decode linear pair -> (i,j), i<j ; wave-uniform (p is per-block)
    int i = 0, rem = p, cnt = NFIELDS - 1;
    while (rem >= cnt) { rem -= cnt; ++i; --cnt; }
    const int j = i + 1 + rem;

    const int b  = blockIdx.x * 256 + threadIdx.x;
    const int xi = x[b * NFIELDS + i];
    const int xj = x[b * NFIELDS + j];

    const float4* va = (const float4*)(V + (((size_t)i * NFIELDS + j) * VOCAB + (size_t)xi) * EDIM);
    const float4* vb = (const float4*)(V + (((size_t)j * NFIELDS + i) * VOCAB + (size_t)xj) * EDIM);

    // 4 independent 16B loads in flight per thread
    const float4 a0 = va[0];
    const float4 a1 = va[1];
    const float4 b0 = vb[0];
    const float4 b1 = vb[1];

    const float dot = a0.x * b0.x + a0.y * b0.y + a0.z * b0.z + a0.w * b0.w
                    + a1.x * b1.x + a1.y * b1.y + a1.z * b1.z + a1.w * b1.w;

    P[(size_t)p * BATCH + b] = dot;   // fully coalesced
}

// ---------------------------------------------------------------------------
// Phase B: one thread per item. 45 coalesced partial reads (unrolled -> all
// outstanding at once) + 10 L gathers (4 MB table, L3-resident) + sigmoid.
// ---------------------------------------------------------------------------
__global__ __launch_bounds__(256) void ffm_reduce(
    const int*   __restrict__ x,
    const float* __restrict__ bias,
    const float* __restrict__ L,    // (NFIELDS, VOCAB)
    const float* __restrict__ P,    // (NPAIR, BATCH)
    float*       __restrict__ out)  // (BATCH, 1)
{
    const int b = blockIdx.x * 256 + threadIdx.x;

    float s = bias[0];

    #pragma unroll
    for (int p = 0; p < NPAIR; ++p)
        s += P[(size_t)p * BATCH + b];       // coalesced columns

    #pragma unroll
    for (int i = 0; i < NFIELDS; ++i)
        s += L[(size_t)i * VOCAB + (size_t)x[b * NFIELDS + i]];

    out[b] = 1.0f / (1.0f + expf(-s));
}

extern "C" void kernel_launch(void* const* d_in, const int* in_sizes, int n_in,
                              void* d_out, int out_size, void* d_ws, size_t ws_size,
                              hipStream_t stream) {
    const int*   x    = (const int*)  d_in[0];
    const float* bias = (const float*)d_in[1];
    const float* L    = (const float*)d_in[2];
    const float* V    = (const float*)d_in[3];
    float*       out  = (float*)d_out;
    float*       P    = (float*)d_ws;        // 45*16384*4 B = 2.95 MB << ws_size

    dim3 gridA(BATCH / 256, NPAIR);
    ffm_pairs<<<gridA, 256, 0, stream>>>(x, V, P);
    ffm_reduce<<<BATCH / 256, 256, 0, stream>>>(x, bias, L, P, out);
}

// Round 3
// 390.317 us; speedup vs baseline: 1.0232x; 1.0232x over previous
//
#include <hip/hip_runtime.h>
#include <math.h>

#define NFIELDS 10
#define VOCAB   100000
#define EDIM    8
#define BATCH   16384
#define NPAIR   45   // 10*9/2

// One 64-lane wave per batch item (measured-best structure, round 1).
// lanes [0,45): one (i,j) pair each -> dot(V[i,j,x[b,i],:], V[j,i,x[b,j],:])
//               4 independent 16B gathers in flight per lane.
// lanes [45,55): one first-order term each -> L[i, x[b,i]]
// 6-step shuffle reduction; lane 0 writes sigmoid(bias + sum).
//
// Roofline note: traffic is dominated by unique 128B-line touches in the
// 320 MB V table: ~12k lines/slice x 90 slices ~= 138 MB/launch (repeats are
// L3 hits). That is the structural floor; this kernel is BW-bound on it.
__global__ __launch_bounds__(256) void ffm_kernel(
    const int*   __restrict__ x,     // (BATCH, NFIELDS)
    const float* __restrict__ bias,  // scalar
    const float* __restrict__ L,     // (NFIELDS, VOCAB)
    const float* __restrict__ V,     // (NFIELDS, NFIELDS, VOCAB, EDIM)
    float*       __restrict__ out)   // (BATCH, 1)
{
    const int lane = threadIdx.x & 63;
    const int wave = threadIdx.x >> 6;
    const int b    = blockIdx.x * 4 + wave;   // grid sized exactly: BATCH/4 blocks

    float acc = 0.0f;

    if (lane < NPAIR) {
        // linear pair index -> (i,j) with i<j (F=10)
        int p = lane;
        int i = 0;
        int cnt = NFIELDS - 1;
        while (p >= cnt) { p -= cnt; ++i; --cnt; }
        const int j = i + 1 + p;

        const int xi = x[b * NFIELDS + i];
        const int xj = x[b * NFIELDS + j];

        const float* va = V + (((size_t)i * NFIELDS + j) * VOCAB + (size_t)xi) * EDIM;
        const float* vb = V + (((size_t)j * NFIELDS + i) * VOCAB + (size_t)xj) * EDIM;

        // rows are 32B-aligned -> float4 loads are legal; 4 independent misses
        const float4 a0 = ((const float4*)va)[0];
        const float4 a1 = ((const float4*)va)[1];
        const float4 b0 = ((const float4*)vb)[0];
        const float4 b1 = ((const float4*)vb)[1];

        acc = a0.x * b0.x + a0.y * b0.y + a0.z * b0.z + a0.w * b0.w
            + a1.x * b1.x + a1.y * b1.y + a1.z * b1.z + a1.w * b1.w;
    } else if (lane < NPAIR + NFIELDS) {
        const int i  = lane - NPAIR;
        const int xi = x[b * NFIELDS + i];
        acc = L[(size_t)i * VOCAB + (size_t)xi];
    }

    // 64-lane butterfly sum
    #pragma unroll
    for (int off = 32; off > 0; off >>= 1)
        acc += __shfl_down(acc, off, 64);

    if (lane == 0) {
        const float logit = acc + bias[0];
        out[b] = 1.0f / (1.0f + expf(-logit));
    }
}

extern "C" void kernel_launch(void* const* d_in, const int* in_sizes, int n_in,
                              void* d_out, int out_size, void* d_ws, size_t ws_size,
                              hipStream_t stream) {
    const int*   x    = (const int*)  d_in[0];
    const float* bias = (const float*)d_in[1];
    const float* L    = (const float*)d_in[2];
    const float* V    = (const float*)d_in[3];
    float*       out  = (float*)d_out;

    const int blocks = BATCH / 4;   // 4 waves (items) per 256-thread block
    ffm_kernel<<<blocks, 256, 0, stream>>>(x, bias, L, V, out);
}